// Round 1
// baseline (1155.053 us; speedup 1.0000x reference)
//
#include <hip/hip_runtime.h>
#include <hip/hip_bf16.h>

#define TOKENS 32768
#define NEXP   16
#define HID    2048
#define IMD    1408
#define BM 128
#define BN 128
#define BK 32

typedef __bf16 bf16x8 __attribute__((ext_vector_type(8)));
typedef float  f32x4  __attribute__((ext_vector_type(4)));
typedef unsigned short u16x8 __attribute__((ext_vector_type(8)));

using gptr1_t = const __attribute__((address_space(1))) void*;
using lptr3_t = __attribute__((address_space(3))) void*;

static __device__ __forceinline__ unsigned short f2bf(float f) {
  unsigned int x = __builtin_bit_cast(unsigned int, f);
  x += 0x7fffu + ((x >> 16) & 1u);   // round-to-nearest-even
  return (unsigned short)(x >> 16);
}
static __device__ __forceinline__ float bf2f(unsigned short u) {
  unsigned int x = ((unsigned int)u) << 16;
  return __builtin_bit_cast(float, x);
}

static __device__ __forceinline__ void gload16(const void* g, void* l) {
  __builtin_amdgcn_global_load_lds((gptr1_t)g, (lptr3_t)l, 16, 0, 0);
}

// ---------------- f32 -> bf16 straight convert (x) ----------------
__global__ __launch_bounds__(256)
void convert_kernel(const float* __restrict__ in, unsigned short* __restrict__ out, size_t n)
{
  size_t i = ((size_t)blockIdx.x * blockDim.x + threadIdx.x) * 8;
  if (i >= n) return;
  float4 a = *(const float4*)(in + i);
  float4 b = *(const float4*)(in + i + 4);
  u16x8 o;
  o[0] = f2bf(a.x); o[1] = f2bf(a.y); o[2] = f2bf(a.z); o[3] = f2bf(a.w);
  o[4] = f2bf(b.x); o[5] = f2bf(b.y); o[6] = f2bf(b.z); o[7] = f2bf(b.w);
  *(u16x8*)(out + i) = o;
}

// ------------- f32 [E][K][N] -> bf16 [E][N][K] transpose-convert -------------
__global__ __launch_bounds__(256)
void transpose_conv_kernel(const float* __restrict__ in, unsigned short* __restrict__ out,
                           int K, int N)
{
  __shared__ float tile[32][33];
  const int e = blockIdx.z;
  const float* ip = in + (size_t)e * K * N;
  unsigned short* op = out + (size_t)e * K * N;
  const int c0 = blockIdx.x * 32, r0 = blockIdx.y * 32;
  const int tx = threadIdx.x, ty = threadIdx.y;
#pragma unroll
  for (int i = 0; i < 4; ++i)
    tile[ty + 8 * i][tx] = ip[(size_t)(r0 + ty + 8 * i) * N + c0 + tx];
  __syncthreads();
#pragma unroll
  for (int i = 0; i < 4; ++i)
    op[(size_t)(c0 + ty + 8 * i) * K + r0 + tx] = f2bf(tile[tx][ty + 8 * i]);
}

// ---------------- grouped GEMM, m97 structure ----------------
// A  [Mtot][K] bf16 row-major, rows grouped by expert
// Bt [E][N][K] bf16 (transposed weights: K contiguous)
// MODE 0: Hc[row][col] = bf16(silu(acc))
// MODE 1: Hc[row][col] = bf16(bf2f(Hc) * acc)
// MODE 2: Cf[row][col] = acc (f32)
template<int MODE>
__global__ __launch_bounds__(256)
void gemm_kernel(const unsigned short* __restrict__ A,
                 const unsigned short* __restrict__ Bt,
                 unsigned short* __restrict__ Hc,
                 float* __restrict__ Cf,
                 const int* __restrict__ gs,
                 int K, int N)
{
  __shared__ __align__(16) unsigned short lds[2][2][BM * BK];

  const int rt = blockIdx.y, ct = blockIdx.x;
  const int row0 = rt * BM;

  // expert for this row tile (group boundaries are 128-aligned in this problem)
  int e = 0;
  {
    int a0 = 0;
    for (int i = 0; i < NEXP; ++i) { int s = gs[i]; if (row0 < a0 + s) { e = i; break; } a0 += s; }
  }

  const unsigned short* Ap = A + (size_t)row0 * K;
  const unsigned short* Bp = Bt + (size_t)e * K * N + (size_t)ct * BN * K;

  const int tid = threadIdx.x;
  const int wave = tid >> 6, lane = tid & 63;
  const int wr = wave >> 1, wc = wave & 1;     // 2x2 wave grid, 64x64 per wave
  const int fr = lane & 15;                    // fragment row/col
  const int fk = (lane >> 4) * 8;              // fragment k offset

  const int srow = wave * 32 + (lane >> 2);    // staging: wave covers 32 rows
  const int scol = (lane & 3) * 8;

  f32x4 acc[4][4] = {};

  const int nt = K / BK;

  auto stage = [&](int buf, int t) {
    const int k0 = t * BK;
    const unsigned short* ga = Ap + (size_t)srow * K + k0 + scol;
    unsigned short* la = &lds[buf][0][wave * 32 * BK];
    gload16(ga, la);
    gload16(ga + (size_t)16 * K, la + 16 * BK);
    const unsigned short* gb = Bp + (size_t)srow * K + k0 + scol;
    unsigned short* lb = &lds[buf][1][wave * 32 * BK];
    gload16(gb, lb);
    gload16(gb + (size_t)16 * K, lb + 16 * BK);
  };

  stage(0, 0);
  __syncthreads();

  for (int t = 0; t < nt; ++t) {
    const int cur = t & 1;
    if (t + 1 < nt) stage(cur ^ 1, t + 1);
    const unsigned short* Ab = &lds[cur][0][0];
    const unsigned short* Bb = &lds[cur][1][0];
    bf16x8 a[4], b[4];
#pragma unroll
    for (int m = 0; m < 4; ++m)
      a[m] = *(const bf16x8*)(Ab + (wr * 64 + m * 16 + fr) * BK + fk);
#pragma unroll
    for (int n = 0; n < 4; ++n)
      b[n] = *(const bf16x8*)(Bb + (wc * 64 + n * 16 + fr) * BK + fk);
#pragma unroll
    for (int m = 0; m < 4; ++m)
#pragma unroll
      for (int n = 0; n < 4; ++n)
        acc[m][n] = __builtin_amdgcn_mfma_f32_16x16x32_bf16(a[m], b[n], acc[m][n], 0, 0, 0);
    __syncthreads();
  }

  // epilogue: C/D layout col = lane&15, row = (lane>>4)*4 + r  (m89-verified)
  const int orow = row0 + wr * 64 + (lane >> 4) * 4;
  const int ocol = ct * BN + wc * 64 + fr;
#pragma unroll
  for (int m = 0; m < 4; ++m) {
#pragma unroll
    for (int n = 0; n < 4; ++n) {
      f32x4 v = acc[m][n];
      const int col = ocol + n * 16;
#pragma unroll
      for (int r = 0; r < 4; ++r) {
        const int row = orow + m * 16 + r;
        if constexpr (MODE == 0) {
          float g = v[r];
          float s = g / (1.f + __expf(-g));
          Hc[(size_t)row * N + col] = f2bf(s);
        } else if constexpr (MODE == 1) {
          float hv = bf2f(Hc[(size_t)row * N + col]) * v[r];
          Hc[(size_t)row * N + col] = f2bf(hv);
        } else {
          Cf[(size_t)row * N + col] = v[r];
        }
      }
    }
  }
}

extern "C" void kernel_launch(void* const* d_in, const int* in_sizes, int n_in,
                              void* d_out, int out_size, void* d_ws, size_t ws_size,
                              hipStream_t stream)
{
  const float* x  = (const float*)d_in[0];
  const float* wg = (const float*)d_in[1];
  const float* wu = (const float*)d_in[2];
  const float* wd = (const float*)d_in[3];
  const int*   gs = (const int*)d_in[4];
  float* out = (float*)d_out;

  // workspace layout (bytes): xb 134.2M | wT 92.3M | h 92.3M  -> 318.8 MB
  char* ws = (char*)d_ws;
  unsigned short* xb = (unsigned short*)ws;
  size_t off = (size_t)TOKENS * HID * 2;
  unsigned short* wT = (unsigned short*)(ws + off);
  off += (size_t)NEXP * HID * IMD * 2;
  unsigned short* h = (unsigned short*)(ws + off);
  off += (size_t)TOKENS * IMD * 2;
  if (ws_size < off) return;  // workspace too small; fail cleanly

  // x -> bf16
  convert_kernel<<<TOKENS * HID / (256 * 8), 256, 0, stream>>>(x, xb, (size_t)TOKENS * HID);

  // gate pass
  transpose_conv_kernel<<<dim3(IMD / 32, HID / 32, NEXP), dim3(32, 8), 0, stream>>>(wg, wT, HID, IMD);
  gemm_kernel<0><<<dim3(IMD / BN, TOKENS / BM), 256, 0, stream>>>(xb, wT, h, nullptr, gs, HID, IMD);

  // up pass (h *= up)
  transpose_conv_kernel<<<dim3(IMD / 32, HID / 32, NEXP), dim3(32, 8), 0, stream>>>(wu, wT, HID, IMD);
  gemm_kernel<1><<<dim3(IMD / BN, TOKENS / BM), 256, 0, stream>>>(xb, wT, h, nullptr, gs, HID, IMD);

  // down pass
  transpose_conv_kernel<<<dim3(HID / 32, IMD / 32, NEXP), dim3(32, 8), 0, stream>>>(wd, wT, IMD, HID);
  gemm_kernel<2><<<dim3(HID / BN, TOKENS / BM), 256, 0, stream>>>(h, wT, nullptr, out, gs, IMD, HID);
}

// Round 2
// 933.927 us; speedup vs baseline: 1.2368x; 1.2368x over previous
//
#include <hip/hip_runtime.h>
#include <hip/hip_bf16.h>

#define TOKENS 32768
#define NEXP   16
#define HID    2048
#define IMD    1408
#define BM 256
#define BK 32

typedef __bf16 bf16x8 __attribute__((ext_vector_type(8)));
typedef float  f32x4  __attribute__((ext_vector_type(4)));
typedef unsigned short u16x8 __attribute__((ext_vector_type(8)));

using gptr1_t = const __attribute__((address_space(1))) void*;
using lptr3_t = __attribute__((address_space(3))) void*;

static __device__ __forceinline__ unsigned short f2bf(float f) {
  unsigned int x = __builtin_bit_cast(unsigned int, f);
  x += 0x7fffu + ((x >> 16) & 1u);   // round-to-nearest-even
  return (unsigned short)(x >> 16);
}
static __device__ __forceinline__ float bf2f(unsigned short u) {
  unsigned int x = ((unsigned int)u) << 16;
  return __builtin_bit_cast(float, x);
}
static __device__ __forceinline__ void gload16(const void* g, void* l) {
  __builtin_amdgcn_global_load_lds((gptr1_t)g, (lptr3_t)l, 16, 0, 0);
}
static __device__ __forceinline__ void vwait(int n) {
  switch (n) {
    case 0:  asm volatile("s_waitcnt vmcnt(0)" ::: "memory"); break;
    case 3:  asm volatile("s_waitcnt vmcnt(3)" ::: "memory"); break;
    case 4:  asm volatile("s_waitcnt vmcnt(4)" ::: "memory"); break;
    case 6:  asm volatile("s_waitcnt vmcnt(6)" ::: "memory"); break;
    default: asm volatile("s_waitcnt vmcnt(8)" ::: "memory"); break;
  }
}

// ---------------- f32 -> bf16 straight convert (x) ----------------
__global__ __launch_bounds__(256)
void convert_kernel(const float* __restrict__ in, unsigned short* __restrict__ out, size_t n)
{
  size_t i = ((size_t)blockIdx.x * blockDim.x + threadIdx.x) * 8;
  if (i >= n) return;
  float4 a = *(const float4*)(in + i);
  float4 b = *(const float4*)(in + i + 4);
  u16x8 o;
  o[0] = f2bf(a.x); o[1] = f2bf(a.y); o[2] = f2bf(a.z); o[3] = f2bf(a.w);
  o[4] = f2bf(b.x); o[5] = f2bf(b.y); o[6] = f2bf(b.z); o[7] = f2bf(b.w);
  *(u16x8*)(out + i) = o;
}

// ------------- f32 [E][K][N] -> bf16 [E][N][K] transpose-convert -------------
__global__ __launch_bounds__(256)
void transpose_conv_kernel(const float* __restrict__ in, unsigned short* __restrict__ out,
                           int K, int N)
{
  __shared__ float tile[32][33];
  const int e = blockIdx.z;
  const float* ip = in + (size_t)e * K * N;
  unsigned short* op = out + (size_t)e * K * N;
  const int c0 = blockIdx.x * 32, r0 = blockIdx.y * 32;
  const int tx = threadIdx.x, ty = threadIdx.y;
#pragma unroll
  for (int i = 0; i < 4; ++i)
    tile[ty + 8 * i][tx] = ip[(size_t)(r0 + ty + 8 * i) * N + c0 + tx];
  __syncthreads();
#pragma unroll
  for (int i = 0; i < 4; ++i)
    op[(size_t)(c0 + ty + 8 * i) * K + r0 + tx] = f2bf(tile[tx][ty + 8 * i]);
}

// ---------------- grouped GEMM, 256-row tile, 4-deep pipelined ----------------
// A  [Mtot][K] bf16 row-major (rows grouped by expert, 2048/expert)
// B* [E][N][K] bf16 (transposed weights: K contiguous)
// MODE 0: fused gate+up (B0=gate, B1=up), BN=128: h = bf16(silu(g)*u)
// MODE 1: down, BN=256: Cf = acc (f32)
// MODE 2: gate only, BN=128: h = bf16(silu(acc))     (fallback path)
// MODE 3: up RMW,   BN=128: h = bf16(bf2f(h)*acc)    (fallback path)
template<int MODE>
__global__ __launch_bounds__(512, 2)
void gemm_kernel(const unsigned short* __restrict__ A,
                 const unsigned short* __restrict__ B0,
                 const unsigned short* __restrict__ B1,
                 unsigned short* __restrict__ Hc,
                 float* __restrict__ Cf,
                 const int* __restrict__ gs,
                 int K, int N)
{
  constexpr int BN    = (MODE == 1) ? 256 : 128;
  constexpr int NPH   = (MODE == 0 || MODE == 1) ? 2 : 1;
  constexpr int BROWS = (MODE == 2 || MODE == 3) ? 128 : 256;
  constexpr int IPT   = (BROWS == 256) ? 4 : 3;   // gload16 instrs per K-tile per wave
  constexpr int NRT   = TOKENS / BM;              // 128 row tiles

  __shared__ __align__(16) unsigned short lA[4][BM * BK];    // 64 KiB
  __shared__ __align__(16) unsigned short lB[4][256 * BK];   // 64 KiB

  // bijective XCD swizzle (all our grids are %8==0); row-tile fastest
  const int nwg = gridDim.x;
  const int q = nwg >> 3;
  const int wgid = (blockIdx.x & 7) * q + (blockIdx.x >> 3);
  const int rt = wgid % NRT;
  const int ct = wgid / NRT;
  const int row0 = rt * BM;

  int e = 0;
  { int a0 = 0;
    for (int i = 0; i < NEXP; ++i) { int s = gs[i]; if (row0 < a0 + s) { e = i; break; } a0 += s; } }

  const unsigned short* Ap = A + (size_t)row0 * K;
  const unsigned short* Bg = B0 + (size_t)e * N * K + (size_t)ct * BN * K;
  const unsigned short* Bu = (MODE == 0) ? (B1 + (size_t)e * N * K + (size_t)ct * BN * K) : nullptr;

  const int tid = threadIdx.x;
  const int lane = tid & 63, wave = tid >> 6;
  const int wr = wave >> 1, wc = wave & 1;     // 4 M-waves x 2 N-waves
  const int fr = lane & 15, fq = lane >> 4;
  const int srow = lane >> 2, scol = (lane & 3) * 8;

  const int nt = K / BK;

  auto stageA = [&](int t) {
    const int k0 = t * BK;
    unsigned short* la = &lA[t & 3][(wave * 32) * BK];
    const unsigned short* ga = Ap + (size_t)(wave * 32 + srow) * K + k0 + scol;
    gload16(ga, la);
    gload16(ga + (size_t)16 * K, la + 16 * BK);
  };
  auto stageB = [&](int t) {
    const int k0 = t * BK;
    if constexpr (BROWS == 256) {
      unsigned short* lb = &lB[t & 3][(wave * 32) * BK];
      const unsigned short* gsrc;
      if constexpr (MODE == 0)
        gsrc = ((wave < 4) ? Bg : Bu) + (size_t)((wave & 3) * 32 + srow) * K + k0 + scol;
      else
        gsrc = Bg + (size_t)(wave * 32 + srow) * K + k0 + scol;
      gload16(gsrc, lb);
      gload16(gsrc + (size_t)16 * K, lb + 16 * BK);
    } else {
      unsigned short* lb = &lB[t & 3][(wave * 16) * BK];
      const unsigned short* gsrc = Bg + (size_t)(wave * 16 + srow) * K + k0 + scol;
      gload16(gsrc, lb);
    }
  };

  f32x4 acc[4][NPH][4] = {};

  // prologue: 3 K-tiles in flight
  stageA(0); stageB(0);
  stageA(1); stageB(1);
  stageA(2); stageB(2);
  vwait(2 * IPT);                 // tile 0 landed, tiles 1..2 in flight
  __builtin_amdgcn_s_barrier();

  for (int t = 0; t < nt; ++t) {
    const unsigned short* Ab = lA[t & 3];
    const unsigned short* Bb = lB[t & 3];
    bf16x8 a[4], b[4];
#pragma unroll
    for (int m = 0; m < 4; ++m)
      a[m] = *(const bf16x8*)(Ab + (wr * 64 + m * 16 + fr) * BK + fq * 8);
    {
      const int bbase = (MODE == 1) ? (wc * 128) : (wc * 64);
#pragma unroll
      for (int n = 0; n < 4; ++n)
        b[n] = *(const bf16x8*)(Bb + (bbase + n * 16 + fr) * BK + fq * 8);
    }
    if (t + 3 < nt) stageA(t + 3);
    __builtin_amdgcn_s_barrier();
    __builtin_amdgcn_s_setprio(1);
#pragma unroll
    for (int m = 0; m < 4; ++m)
#pragma unroll
      for (int n = 0; n < 4; ++n)
        acc[m][0][n] = __builtin_amdgcn_mfma_f32_16x16x32_bf16(a[m], b[n], acc[m][0][n], 0, 0, 0);
    __builtin_amdgcn_s_setprio(0);

    if constexpr (NPH == 2) {
      bf16x8 b2[4];
      const int b2base = (MODE == 1) ? (wc * 128 + 64) : (128 + wc * 64);
#pragma unroll
      for (int n = 0; n < 4; ++n)
        b2[n] = *(const bf16x8*)(Bb + (b2base + n * 16 + fr) * BK + fq * 8);
      if (t + 3 < nt) stageB(t + 3);
      __builtin_amdgcn_s_barrier();
      __builtin_amdgcn_s_setprio(1);
#pragma unroll
      for (int m = 0; m < 4; ++m)
#pragma unroll
        for (int n = 0; n < 4; ++n)
          acc[m][1][n] = __builtin_amdgcn_mfma_f32_16x16x32_bf16(a[m], b2[n], acc[m][1][n], 0, 0, 0);
      __builtin_amdgcn_s_setprio(0);
    } else {
      if (t + 3 < nt) stageB(t + 3);
    }

    if (t + 1 < nt) {
      int beyond = nt - 2 - t;          // K-tiles in flight beyond t+1
      if (beyond > 2) beyond = 2;
      vwait(beyond * IPT);              // counted: never drain prefetch mid-loop
      __builtin_amdgcn_s_barrier();
    }
  }

  // epilogue: C/D layout col = lane&15, row = (lane>>4)*4 + r  (m89-verified)
  const int orow0 = row0 + wr * 64 + fq * 4;
#pragma unroll
  for (int m = 0; m < 4; ++m) {
#pragma unroll
    for (int n = 0; n < 4; ++n) {
      if constexpr (MODE == 0) {
        const int col = ct * BN + wc * 64 + n * 16 + fr;
        f32x4 g = acc[m][0][n], u = acc[m][1][n];
#pragma unroll
        for (int r = 0; r < 4; ++r) {
          const int row = orow0 + m * 16 + r;
          float gv = g[r];
          float s = gv / (1.f + __expf(-gv)) * u[r];
          Hc[(size_t)row * N + col] = f2bf(s);
        }
      } else if constexpr (MODE == 1) {
#pragma unroll
        for (int p = 0; p < 2; ++p) {
          const int col = ct * BN + wc * 128 + p * 64 + n * 16 + fr;
          f32x4 v = acc[m][p][n];
#pragma unroll
          for (int r = 0; r < 4; ++r)
            Cf[(size_t)(orow0 + m * 16 + r) * N + col] = v[r];
        }
      } else if constexpr (MODE == 2) {
        const int col = ct * BN + wc * 64 + n * 16 + fr;
        f32x4 v = acc[m][0][n];
#pragma unroll
        for (int r = 0; r < 4; ++r) {
          float gv = v[r];
          Hc[(size_t)(orow0 + m * 16 + r) * N + col] = f2bf(gv / (1.f + __expf(-gv)));
        }
      } else {
        const int col = ct * BN + wc * 64 + n * 16 + fr;
        f32x4 v = acc[m][0][n];
#pragma unroll
        for (int r = 0; r < 4; ++r) {
          const size_t idx = (size_t)(orow0 + m * 16 + r) * N + col;
          Hc[idx] = f2bf(bf2f(Hc[idx]) * v[r]);
        }
      }
    }
  }
}

extern "C" void kernel_launch(void* const* d_in, const int* in_sizes, int n_in,
                              void* d_out, int out_size, void* d_ws, size_t ws_size,
                              hipStream_t stream)
{
  const float* x  = (const float*)d_in[0];
  const float* wg = (const float*)d_in[1];
  const float* wu = (const float*)d_in[2];
  const float* wd = (const float*)d_in[3];
  const int*   gs = (const int*)d_in[4];
  float* out = (float*)d_out;

  const size_t SZ_XB = (size_t)TOKENS * HID * 2;        // 134,217,728
  const size_t SZ_W  = (size_t)NEXP * HID * IMD * 2;    //  92,274,688
  const size_t SZ_H  = (size_t)TOKENS * IMD * 2;        //  92,274,688

  char* ws = (char*)d_ws;
  unsigned short* xb = (unsigned short*)ws;

  const int cvt_grid = (int)(((size_t)TOKENS * HID) / (256 * 8));
  convert_kernel<<<cvt_grid, 256, 0, stream>>>(x, xb, (size_t)TOKENS * HID);

  if (ws_size >= SZ_XB + 2 * SZ_W + SZ_H) {
    // fused path: xb | wTg | wTu | h
    unsigned short* wTg = (unsigned short*)(ws + SZ_XB);
    unsigned short* wTu = (unsigned short*)(ws + SZ_XB + SZ_W);
    unsigned short* h   = (unsigned short*)(ws + SZ_XB + 2 * SZ_W);

    transpose_conv_kernel<<<dim3(IMD / 32, HID / 32, NEXP), dim3(32, 8), 0, stream>>>(wg, wTg, HID, IMD);
    transpose_conv_kernel<<<dim3(IMD / 32, HID / 32, NEXP), dim3(32, 8), 0, stream>>>(wu, wTu, HID, IMD);
    gemm_kernel<0><<<(TOKENS / BM) * (IMD / 128), 512, 0, stream>>>(
        xb, wTg, wTu, h, nullptr, gs, HID, IMD);

    transpose_conv_kernel<<<dim3(HID / 32, IMD / 32, NEXP), dim3(32, 8), 0, stream>>>(wd, wTg, IMD, HID);
    gemm_kernel<1><<<(TOKENS / BM) * (HID / 256), 512, 0, stream>>>(
        h, wTg, nullptr, nullptr, out, gs, IMD, HID);
  } else if (ws_size >= SZ_XB + SZ_W + SZ_H) {
    // sequential fallback: xb | wT | h
    unsigned short* wT = (unsigned short*)(ws + SZ_XB);
    unsigned short* h  = (unsigned short*)(ws + SZ_XB + SZ_W);

    transpose_conv_kernel<<<dim3(IMD / 32, HID / 32, NEXP), dim3(32, 8), 0, stream>>>(wg, wT, HID, IMD);
    gemm_kernel<2><<<(TOKENS / BM) * (IMD / 128), 512, 0, stream>>>(
        xb, wT, nullptr, h, nullptr, gs, HID, IMD);

    transpose_conv_kernel<<<dim3(IMD / 32, HID / 32, NEXP), dim3(32, 8), 0, stream>>>(wu, wT, HID, IMD);
    gemm_kernel<3><<<(TOKENS / BM) * (IMD / 128), 512, 0, stream>>>(
        xb, wT, nullptr, h, nullptr, gs, HID, IMD);

    transpose_conv_kernel<<<dim3(HID / 32, IMD / 32, NEXP), dim3(32, 8), 0, stream>>>(wd, wT, IMD, HID);
    gemm_kernel<1><<<(TOKENS / BM) * (HID / 256), 512, 0, stream>>>(
        h, wT, nullptr, nullptr, out, gs, IMD, HID);
  }
}

// Round 3
// 919.558 us; speedup vs baseline: 1.2561x; 1.0156x over previous
//
#include <hip/hip_runtime.h>
#include <hip/hip_bf16.h>

#define TOKENS 32768
#define NEXP   16
#define HID    2048
#define IMD    1408
#define BM 256
#define BK 32

typedef __bf16 bf16x8 __attribute__((ext_vector_type(8)));
typedef float  f32x4  __attribute__((ext_vector_type(4)));
typedef unsigned short u16x8 __attribute__((ext_vector_type(8)));

using gptr1_t = const __attribute__((address_space(1))) void*;
using lptr3_t = __attribute__((address_space(3))) void*;

static __device__ __forceinline__ unsigned short f2bf(float f) {
  unsigned int x = __builtin_bit_cast(unsigned int, f);
  x += 0x7fffu + ((x >> 16) & 1u);   // round-to-nearest-even
  return (unsigned short)(x >> 16);
}
static __device__ __forceinline__ float bf2f(unsigned short u) {
  unsigned int x = ((unsigned int)u) << 16;
  return __builtin_bit_cast(float, x);
}
static __device__ __forceinline__ void gload16(const void* g, void* l) {
  __builtin_amdgcn_global_load_lds((gptr1_t)g, (lptr3_t)l, 16, 0, 0);
}
static __device__ __forceinline__ void vwait(int n) {
  switch (n) {
    case 0:  asm volatile("s_waitcnt vmcnt(0)" ::: "memory"); break;
    case 3:  asm volatile("s_waitcnt vmcnt(3)" ::: "memory"); break;
    case 4:  asm volatile("s_waitcnt vmcnt(4)" ::: "memory"); break;
    case 6:  asm volatile("s_waitcnt vmcnt(6)" ::: "memory"); break;
    default: asm volatile("s_waitcnt vmcnt(8)" ::: "memory"); break;
  }
}

// ---------------- f32 -> bf16 straight convert (x) ----------------
__global__ __launch_bounds__(256)
void convert_kernel(const float* __restrict__ in, unsigned short* __restrict__ out, size_t n)
{
  size_t i = ((size_t)blockIdx.x * blockDim.x + threadIdx.x) * 8;
  if (i >= n) return;
  float4 a = *(const float4*)(in + i);
  float4 b = *(const float4*)(in + i + 4);
  u16x8 o;
  o[0] = f2bf(a.x); o[1] = f2bf(a.y); o[2] = f2bf(a.z); o[3] = f2bf(a.w);
  o[4] = f2bf(b.x); o[5] = f2bf(b.y); o[6] = f2bf(b.z); o[7] = f2bf(b.w);
  *(u16x8*)(out + i) = o;
}

// ------------- f32 [E][K][N] -> bf16 [E][N][K] transpose-convert -------------
__global__ __launch_bounds__(256)
void transpose_conv_kernel(const float* __restrict__ in, unsigned short* __restrict__ out,
                           int K, int N)
{
  __shared__ float tile[32][33];
  const int e = blockIdx.z;
  const float* ip = in + (size_t)e * K * N;
  unsigned short* op = out + (size_t)e * K * N;
  const int c0 = blockIdx.x * 32, r0 = blockIdx.y * 32;
  const int tx = threadIdx.x, ty = threadIdx.y;
#pragma unroll
  for (int i = 0; i < 4; ++i)
    tile[ty + 8 * i][tx] = ip[(size_t)(r0 + ty + 8 * i) * N + c0 + tx];
  __syncthreads();
#pragma unroll
  for (int i = 0; i < 4; ++i)
    op[(size_t)(c0 + ty + 8 * i) * K + r0 + tx] = f2bf(tile[tx][ty + 8 * i]);
}

// ---------------- grouped GEMM, 256-row tile, 4-deep pipelined ----------------
// LDS slot-swizzle (T2 adapted to BK=32): logical 16B slot s of row r is stored
// at LDS slot s ^ ((r>>1)&3). Applied on BOTH sides (rule #21): staged via
// pre-swizzled global source column; read via XOR'd fragment address.
// A  [Mtot][K] bf16 row-major (rows grouped by expert, 2048/expert)
// B* [E][N][K] bf16 (transposed weights: K contiguous)
// MODE 0: fused gate+up (B0=gate, B1=up), BN=128: h = bf16(silu(g)*u)
// MODE 1: down, BN=256: Cf = acc (f32)
// MODE 2: gate only, BN=128: h = bf16(silu(acc))     (fallback path)
// MODE 3: up RMW,   BN=128: h = bf16(bf2f(h)*acc)    (fallback path)
template<int MODE>
__global__ __launch_bounds__(512, 2)
void gemm_kernel(const unsigned short* __restrict__ A,
                 const unsigned short* __restrict__ B0,
                 const unsigned short* __restrict__ B1,
                 unsigned short* __restrict__ Hc,
                 float* __restrict__ Cf,
                 const int* __restrict__ gs,
                 int K, int N)
{
  constexpr int BN    = (MODE == 1) ? 256 : 128;
  constexpr int NPH   = (MODE == 0 || MODE == 1) ? 2 : 1;
  constexpr int BROWS = (MODE == 2 || MODE == 3) ? 128 : 256;
  constexpr int IPT   = (BROWS == 256) ? 4 : 3;   // gload16 instrs per K-tile per wave
  constexpr int NRT   = TOKENS / BM;              // 128 row tiles

  __shared__ __align__(16) unsigned short lA[4][BM * BK];    // 64 KiB
  __shared__ __align__(16) unsigned short lB[4][256 * BK];   // 64 KiB

  // bijective XCD swizzle (all our grids are %8==0); row-tile fastest
  const int nwg = gridDim.x;
  const int q = nwg >> 3;
  const int wgid = (blockIdx.x & 7) * q + (blockIdx.x >> 3);
  const int rt = wgid % NRT;
  const int ct = wgid / NRT;
  const int row0 = rt * BM;

  int e = 0;
  { int a0 = 0;
    for (int i = 0; i < NEXP; ++i) { int s = gs[i]; if (row0 < a0 + s) { e = i; break; } a0 += s; } }

  const unsigned short* Ap = A + (size_t)row0 * K;
  const unsigned short* Bg = B0 + (size_t)e * N * K + (size_t)ct * BN * K;
  const unsigned short* Bu = (MODE == 0) ? (B1 + (size_t)e * N * K + (size_t)ct * BN * K) : nullptr;

  const int tid = threadIdx.x;
  const int lane = tid & 63, wave = tid >> 6;
  const int wr = wave >> 1, wc = wave & 1;     // 4 M-waves x 2 N-waves
  const int fr = lane & 15, fq = lane >> 4;
  const int srow = lane >> 2;
  // pre-swizzled staging source column: slot (lane&3) of row srow holds
  // global slot (lane&3) ^ ((srow>>1)&3). Invariant under +16-row offsets.
  const int scol = (((lane & 3) ^ ((srow >> 1) & 3)) * 8);
  // swizzled fragment-read slot: fragment row bases are multiples of 16, so
  // f(row) = (fr>>1)&3 — per-lane constant.
  const int fsw = (fq ^ ((fr >> 1) & 3)) * 8;

  const int nt = K / BK;

  auto stageA = [&](int t) {
    const int k0 = t * BK;
    unsigned short* la = &lA[t & 3][(wave * 32) * BK];
    const unsigned short* ga = Ap + (size_t)(wave * 32 + srow) * K + k0 + scol;
    gload16(ga, la);
    gload16(ga + (size_t)16 * K, la + 16 * BK);
  };
  auto stageB = [&](int t) {
    const int k0 = t * BK;
    if constexpr (BROWS == 256) {
      unsigned short* lb = &lB[t & 3][(wave * 32) * BK];
      const unsigned short* gsrc;
      if constexpr (MODE == 0)
        gsrc = ((wave < 4) ? Bg : Bu) + (size_t)((wave & 3) * 32 + srow) * K + k0 + scol;
      else
        gsrc = Bg + (size_t)(wave * 32 + srow) * K + k0 + scol;
      gload16(gsrc, lb);
      gload16(gsrc + (size_t)16 * K, lb + 16 * BK);
    } else {
      unsigned short* lb = &lB[t & 3][(wave * 16) * BK];
      const unsigned short* gsrc = Bg + (size_t)(wave * 16 + srow) * K + k0 + scol;
      gload16(gsrc, lb);
    }
  };

  f32x4 acc[4][NPH][4] = {};

  // prologue: 3 K-tiles in flight
  stageA(0); stageB(0);
  stageA(1); stageB(1);
  stageA(2); stageB(2);
  vwait(2 * IPT);                 // tile 0 landed, tiles 1..2 in flight
  __builtin_amdgcn_s_barrier();

  for (int t = 0; t < nt; ++t) {
    const unsigned short* Ab = lA[t & 3];
    const unsigned short* Bb = lB[t & 3];
    bf16x8 a[4], b[4];
#pragma unroll
    for (int m = 0; m < 4; ++m)
      a[m] = *(const bf16x8*)(Ab + (wr * 64 + m * 16 + fr) * BK + fsw);
    {
      const int bbase = (MODE == 1) ? (wc * 128) : (wc * 64);
#pragma unroll
      for (int n = 0; n < 4; ++n)
        b[n] = *(const bf16x8*)(Bb + (bbase + n * 16 + fr) * BK + fsw);
    }
    if (t + 3 < nt) stageA(t + 3);
    __builtin_amdgcn_s_barrier();
    __builtin_amdgcn_s_setprio(1);
#pragma unroll
    for (int m = 0; m < 4; ++m)
#pragma unroll
      for (int n = 0; n < 4; ++n)
        acc[m][0][n] = __builtin_amdgcn_mfma_f32_16x16x32_bf16(a[m], b[n], acc[m][0][n], 0, 0, 0);
    __builtin_amdgcn_s_setprio(0);

    if constexpr (NPH == 2) {
      bf16x8 b2[4];
      const int b2base = (MODE == 1) ? (wc * 128 + 64) : (128 + wc * 64);
#pragma unroll
      for (int n = 0; n < 4; ++n)
        b2[n] = *(const bf16x8*)(Bb + (b2base + n * 16 + fr) * BK + fsw);
      if (t + 3 < nt) stageB(t + 3);
      __builtin_amdgcn_s_barrier();
      __builtin_amdgcn_s_setprio(1);
#pragma unroll
      for (int m = 0; m < 4; ++m)
#pragma unroll
        for (int n = 0; n < 4; ++n)
          acc[m][1][n] = __builtin_amdgcn_mfma_f32_16x16x32_bf16(a[m], b2[n], acc[m][1][n], 0, 0, 0);
      __builtin_amdgcn_s_setprio(0);
    } else {
      if (t + 3 < nt) stageB(t + 3);
    }

    if (t + 1 < nt) {
      int beyond = nt - 2 - t;          // K-tiles in flight beyond t+1
      if (beyond > 2) beyond = 2;
      vwait(beyond * IPT);              // counted: never drain prefetch mid-loop
      __builtin_amdgcn_s_barrier();
    }
  }

  // epilogue: C/D layout col = lane&15, row = (lane>>4)*4 + r  (m89-verified)
  const int orow0 = row0 + wr * 64 + fq * 4;
#pragma unroll
  for (int m = 0; m < 4; ++m) {
#pragma unroll
    for (int n = 0; n < 4; ++n) {
      if constexpr (MODE == 0) {
        const int col = ct * BN + wc * 64 + n * 16 + fr;
        f32x4 g = acc[m][0][n], u = acc[m][1][n];
#pragma unroll
        for (int r = 0; r < 4; ++r) {
          const int row = orow0 + m * 16 + r;
          float gv = g[r];
          float s = gv / (1.f + __expf(-gv)) * u[r];
          Hc[(size_t)row * N + col] = f2bf(s);
        }
      } else if constexpr (MODE == 1) {
#pragma unroll
        for (int p = 0; p < 2; ++p) {
          const int col = ct * BN + wc * 128 + p * 64 + n * 16 + fr;
          f32x4 v = acc[m][p][n];
#pragma unroll
          for (int r = 0; r < 4; ++r)
            Cf[(size_t)(orow0 + m * 16 + r) * N + col] = v[r];
        }
      } else if constexpr (MODE == 2) {
        const int col = ct * BN + wc * 64 + n * 16 + fr;
        f32x4 v = acc[m][0][n];
#pragma unroll
        for (int r = 0; r < 4; ++r) {
          float gv = v[r];
          Hc[(size_t)(orow0 + m * 16 + r) * N + col] = f2bf(gv / (1.f + __expf(-gv)));
        }
      } else {
        const int col = ct * BN + wc * 64 + n * 16 + fr;
        f32x4 v = acc[m][0][n];
#pragma unroll
        for (int r = 0; r < 4; ++r) {
          const size_t idx = (size_t)(orow0 + m * 16 + r) * N + col;
          Hc[idx] = f2bf(bf2f(Hc[idx]) * v[r]);
        }
      }
    }
  }
}

extern "C" void kernel_launch(void* const* d_in, const int* in_sizes, int n_in,
                              void* d_out, int out_size, void* d_ws, size_t ws_size,
                              hipStream_t stream)
{
  const float* x  = (const float*)d_in[0];
  const float* wg = (const float*)d_in[1];
  const float* wu = (const float*)d_in[2];
  const float* wd = (const float*)d_in[3];
  const int*   gs = (const int*)d_in[4];
  float* out = (float*)d_out;

  const size_t SZ_XB = (size_t)TOKENS * HID * 2;        // 134,217,728
  const size_t SZ_W  = (size_t)NEXP * HID * IMD * 2;    //  92,274,688
  const size_t SZ_H  = (size_t)TOKENS * IMD * 2;        //  92,274,688

  char* ws = (char*)d_ws;
  unsigned short* xb = (unsigned short*)ws;

  const int cvt_grid = (int)(((size_t)TOKENS * HID) / (256 * 8));
  convert_kernel<<<cvt_grid, 256, 0, stream>>>(x, xb, (size_t)TOKENS * HID);

  if (ws_size >= SZ_XB + 2 * SZ_W + SZ_H) {
    // fused path: xb | wTg | wTu | h
    unsigned short* wTg = (unsigned short*)(ws + SZ_XB);
    unsigned short* wTu = (unsigned short*)(ws + SZ_XB + SZ_W);
    unsigned short* h   = (unsigned short*)(ws + SZ_XB + 2 * SZ_W);

    transpose_conv_kernel<<<dim3(IMD / 32, HID / 32, NEXP), dim3(32, 8), 0, stream>>>(wg, wTg, HID, IMD);
    transpose_conv_kernel<<<dim3(IMD / 32, HID / 32, NEXP), dim3(32, 8), 0, stream>>>(wu, wTu, HID, IMD);
    gemm_kernel<0><<<(TOKENS / BM) * (IMD / 128), 512, 0, stream>>>(
        xb, wTg, wTu, h, nullptr, gs, HID, IMD);

    transpose_conv_kernel<<<dim3(HID / 32, IMD / 32, NEXP), dim3(32, 8), 0, stream>>>(wd, wTg, IMD, HID);
    gemm_kernel<1><<<(TOKENS / BM) * (HID / 256), 512, 0, stream>>>(
        h, wTg, nullptr, nullptr, out, gs, IMD, HID);
  } else if (ws_size >= SZ_XB + SZ_W + SZ_H) {
    // sequential fallback: xb | wT | h
    unsigned short* wT = (unsigned short*)(ws + SZ_XB);
    unsigned short* h  = (unsigned short*)(ws + SZ_XB + SZ_W);

    transpose_conv_kernel<<<dim3(IMD / 32, HID / 32, NEXP), dim3(32, 8), 0, stream>>>(wg, wT, HID, IMD);
    gemm_kernel<2><<<(TOKENS / BM) * (IMD / 128), 512, 0, stream>>>(
        xb, wT, nullptr, h, nullptr, gs, HID, IMD);

    transpose_conv_kernel<<<dim3(IMD / 32, HID / 32, NEXP), dim3(32, 8), 0, stream>>>(wu, wT, HID, IMD);
    gemm_kernel<3><<<(TOKENS / BM) * (IMD / 128), 512, 0, stream>>>(
        xb, wT, nullptr, h, nullptr, gs, HID, IMD);

    transpose_conv_kernel<<<dim3(HID / 32, IMD / 32, NEXP), dim3(32, 8), 0, stream>>>(wd, wT, IMD, HID);
    gemm_kernel<1><<<(TOKENS / BM) * (HID / 256), 512, 0, stream>>>(
        h, wT, nullptr, nullptr, out, gs, IMD, HID);
  }
}